// Round 7
// baseline (316.919 us; speedup 1.0000x reference)
//
#include <hip/hip_runtime.h>
#include <stdint.h>

// B=8, Lt=64, Lv=16384, D=256. Inputs fp32 (runtime-sniffed; R4-proven), out per flag.
// ws ~512 MiB (R6 rocprof: 512MiB re-poison fill) -> cache Sc = e[row][t] fp32 (33.5 MB).
#define NB 8
#define LT 64
#define LV 16384
#define DD 256
#define EPSV 1e-6f
#define BF16MAX 3.3895313892515355e38f

typedef unsigned short u16t;
typedef __attribute__((ext_vector_type(8))) short short8;
typedef __attribute__((ext_vector_type(4))) float floatx4;

__device__ __forceinline__ float bf2f(u16t h) {
    union { uint32_t u; float f; } cv; cv.u = ((uint32_t)h) << 16; return cv.f;
}
__device__ __forceinline__ uint32_t asu(float f) { union { float f; uint32_t u; } c; c.f = f; return c.u; }
__device__ __forceinline__ float asf(uint32_t u) { union { uint32_t u; float f; } c; c.u = u; return c.f; }
__device__ __forceinline__ u16t f2bf(float f) {
    uint32_t u = asu(f);
    return (u16t)((u + 0x7fffu + ((u >> 16) & 1u)) >> 16);  // RNE, finite
}
__device__ __forceinline__ float fixnum(float f) {
    if (f != f) return 0.0f;
    if (f > BF16MAX) return BF16MAX;    // clamp so RNE-to-bf16 can't hit inf
    if (f < -BF16MAX) return -BF16MAX;
    return f;
}
__device__ __forceinline__ float load_in(const void* p, long i, int isf32) {
    return isf32 ? ((const float*)p)[i] : bf2f(((const u16t*)p)[i]);
}
// RNE bf16 head; returns bits, sets float value. Residual a - hf is exact.
__device__ __forceinline__ uint32_t bfhead(float a, float& hf) {
    uint32_t u = asu(a);
    uint32_t h = (u + 0x7fffu + ((u >> 16) & 1u)) >> 16;
    hf = asf(h << 16);
    return h;
}

// Fused init: zero stats, init min/max atomic slots, dtype-sniff v.
__global__ __launch_bounds__(256) void k_init(const u16t* v, float* Z,
                                              uint32_t* mnmx, int* flag) {
    int tid = threadIdx.x;
    for (int i = tid; i < 1536; i += 256) Z[i] = 0.0f;
    if (tid < NB) { mnmx[tid * 2] = 0x7f800000u; mnmx[tid * 2 + 1] = 0u; }
    if (tid < 64) {
        int sane = 0;
        for (int i = 0; i < 16; ++i) {
            u16t h = v[tid * 16 + i];
            int ex = (h >> 7) & 0xFF;
            if ((h & 0x7FFF) == 0 || (ex >= 96 && ex < 160)) ++sane;
        }
        #pragma unroll
        for (int o = 1; o < 64; o <<= 1) sane += __shfl_xor(sane, o, 64);
        if (tid == 0) flag[0] = (sane < 900) ? 1 : 0;  // 1 = fp32
    }
}

// tnB[b][t][k] = bf16( l2norm(nan_to_num(t_row)) * 0.5 ), k contiguous.
__global__ void k1_tnorm(const void* t, u16t* tnB, const int* flag) {
    __shared__ float red[256];
    int isf32 = flag[0];
    int row = blockIdx.x;                 // b*64 + r
    int k = threadIdx.x;
    float x = fixnum(load_in(t, (long)row * DD + k, isf32));
    red[k] = x * x;
    __syncthreads();
    for (int s = 128; s > 0; s >>= 1) {
        if (k < s) red[k] += red[k + s];
        __syncthreads();
    }
    float scale = 0.5f / fmaxf(sqrtf(red[0]), EPSV);
    tnB[row * DD + k] = f2bf(x * scale);
}

// MFMA GEMM pass: per wave 32 v-rows x 64 t, K=256. A = v as exact 3-term RNE
// bf16 split, B = tn bf16. Computes e=exp(S), accumulates Z/S1/S2, caches e->Sc.
__global__ __launch_bounds__(256) void k_gemm(const void* v, const u16t* tnB,
                                              float* Sc, float* Z, float* S1,
                                              float* S2, const int* flag) {
    __shared__ u16t ldsT[64 * 264];        // [t][k], +8 pad per row (33 KB)
    __shared__ float zlds[3][4][64];       // block reduction (3 KB)
    int isf32 = flag[0];
    int tid = threadIdx.x, wave = tid >> 6, lane = tid & 63;
    int c16 = lane & 15, q = lane >> 4;
    int b = blockIdx.y, tile = blockIdx.x;
    int rowbase = tile * 128 + wave * 32;  // within b

    {   // stage tn[b] into LDS (64 x 256 u16, padded rows)
        const u16t* src = tnB + (size_t)b * (LT * DD);
        for (int i = tid; i < 2048; i += 256) {
            int tt = i >> 5, k8 = i & 31;
            *(uint4*)&ldsT[tt * 264 + k8 * 8] = *(const uint4*)&src[tt * DD + k8 * 8];
        }
    }
    __syncthreads();

    floatx4 acc[2][4];                     // [mt][nt]
    #pragma unroll
    for (int mt = 0; mt < 2; ++mt)
        #pragma unroll
        for (int nt = 0; nt < 4; ++nt) acc[mt][nt] = (floatx4){0.f, 0.f, 0.f, 0.f};
    float ssqp[2] = {0.f, 0.f};

    for (int kc = 0; kc < 8; ++kc) {
        short8 bf[4];                      // B: tn[t=nt*16+c16][k=kc*32+q*8 ..]
        #pragma unroll
        for (int nt = 0; nt < 4; ++nt)
            bf[nt] = *(const short8*)&ldsT[(nt * 16 + c16) * 264 + kc * 32 + q * 8];

        #pragma unroll
        for (int mt = 0; mt < 2; ++mt) {
            int row = rowbase + mt * 16 + c16;
            float f[8];
            if (isf32) {
                const float* vr = (const float*)v +
                    ((size_t)b * LV + row) * DD + kc * 32 + q * 8;
                float4 p0 = *(const float4*)vr;
                float4 p1 = *(const float4*)(vr + 4);
                f[0]=p0.x; f[1]=p0.y; f[2]=p0.z; f[3]=p0.w;
                f[4]=p1.x; f[5]=p1.y; f[6]=p1.z; f[7]=p1.w;
            } else {
                const u16t* vr = (const u16t*)v +
                    ((size_t)b * LV + row) * DD + kc * 32 + q * 8;
                uint4 u = *(const uint4*)vr;
                f[0]=bf2f((u16t)u.x); f[1]=bf2f((u16t)(u.x>>16));
                f[2]=bf2f((u16t)u.y); f[3]=bf2f((u16t)(u.y>>16));
                f[4]=bf2f((u16t)u.z); f[5]=bf2f((u16t)(u.z>>16));
                f[6]=bf2f((u16t)u.w); f[7]=bf2f((u16t)(u.w>>16));
            }
            #pragma unroll
            for (int i = 0; i < 8; ++i) f[i] = fixnum(f[i]);
            // exact 3-term RNE split: f = h1 + h2 + h3
            union { short8 s; uint32_t u[4]; } a1, a2, a3;
            #pragma unroll
            for (int i = 0; i < 4; ++i) {
                float e0 = f[2*i], e1 = f[2*i+1];
                ssqp[mt] += e0 * e0 + e1 * e1;
                float h10f, h11f, h20f, h21f, dummy;
                uint32_t h10 = bfhead(e0, h10f), h11 = bfhead(e1, h11f);
                float r10 = e0 - h10f,  r11 = e1 - h11f;
                uint32_t h20 = bfhead(r10, h20f), h21 = bfhead(r11, h21f);
                float r20 = r10 - h20f, r21 = r11 - h21f;
                uint32_t h30 = bfhead(r20, dummy), h31 = bfhead(r21, dummy);
                a1.u[i] = h10 | (h11 << 16);
                a2.u[i] = h20 | (h21 << 16);
                a3.u[i] = h30 | (h31 << 16);
            }
            #pragma unroll
            for (int nt = 0; nt < 4; ++nt) {
                acc[mt][nt] = __builtin_amdgcn_mfma_f32_16x16x32_bf16(
                    a1.s, bf[nt], acc[mt][nt], 0, 0, 0);
                acc[mt][nt] = __builtin_amdgcn_mfma_f32_16x16x32_bf16(
                    a2.s, bf[nt], acc[mt][nt], 0, 0, 0);
                acc[mt][nt] = __builtin_amdgcn_mfma_f32_16x16x32_bf16(
                    a3.s, bf[nt], acc[mt][nt], 0, 0, 0);
            }
        }
    }

    // full ||v||^2 per row (row = rowbase + mt*16 + c16 at this lane)
    float ssqf[2];
    #pragma unroll
    for (int mt = 0; mt < 2; ++mt) {
        float s = ssqp[mt];
        s += __shfl_xor(s, 16, 64);
        s += __shfl_xor(s, 32, 64);
        ssqf[mt] = s;
    }
    // fac for this lane's D rows: D row = q*4+reg -> source lane q*4+reg
    float facr[2][4];
    #pragma unroll
    for (int mt = 0; mt < 2; ++mt)
        #pragma unroll
        for (int reg = 0; reg < 4; ++reg) {
            float ss = __shfl(ssqf[mt], q * 4 + reg, 64);
            facr[mt][reg] = 1.0f / fmaxf(sqrtf(ss), EPSV);
        }

    float zacc[4] = {0,0,0,0}, s1acc[4] = {0,0,0,0}, s2acc[4] = {0,0,0,0};
    #pragma unroll
    for (int mt = 0; mt < 2; ++mt)
        #pragma unroll
        for (int reg = 0; reg < 4; ++reg) {
            float e[4], se = 0.f;
            #pragma unroll
            for (int nt = 0; nt < 4; ++nt) {
                e[nt] = __expf(acc[mt][nt][reg] * facr[mt][reg]);
                se += e[nt];
            }
            se += __shfl_xor(se, 1, 64);
            se += __shfl_xor(se, 2, 64);
            se += __shfl_xor(se, 4, 64);
            se += __shfl_xor(se, 8, 64);
            float inv = 1.0f / se;
            // cache e for the scores pass
            size_t srow = (size_t)b * LV + rowbase + mt * 16 + q * 4 + reg;
            #pragma unroll
            for (int nt = 0; nt < 4; ++nt) {
                Sc[srow * LT + nt * 16 + c16] = e[nt];
                float A = e[nt] * inv;
                float w = __expf(0.5f * A);
                zacc[nt] += e[nt]; s1acc[nt] += w; s2acc[nt] += w * A;
            }
        }
    #pragma unroll
    for (int nt = 0; nt < 4; ++nt) {
        zacc[nt]  += __shfl_xor(zacc[nt], 16, 64);  zacc[nt]  += __shfl_xor(zacc[nt], 32, 64);
        s1acc[nt] += __shfl_xor(s1acc[nt], 16, 64); s1acc[nt] += __shfl_xor(s1acc[nt], 32, 64);
        s2acc[nt] += __shfl_xor(s2acc[nt], 16, 64); s2acc[nt] += __shfl_xor(s2acc[nt], 32, 64);
    }
    if (lane < 16) {
        #pragma unroll
        for (int nt = 0; nt < 4; ++nt) {
            zlds[0][wave][nt * 16 + lane] = zacc[nt];
            zlds[1][wave][nt * 16 + lane] = s1acc[nt];
            zlds[2][wave][nt * 16 + lane] = s2acc[nt];
        }
    }
    __syncthreads();
    if (tid < 64) {
        float z  = zlds[0][0][tid] + zlds[0][1][tid] + zlds[0][2][tid] + zlds[0][3][tid];
        float a  = zlds[1][0][tid] + zlds[1][1][tid] + zlds[1][2][tid] + zlds[1][3][tid];
        float s2 = zlds[2][0][tid] + zlds[2][1][tid] + zlds[2][2][tid] + zlds[2][3][tid];
        atomicAdd(&Z[b * LT + tid], z);
        atomicAdd(&S1[b * LT + tid], a);
        atomicAdd(&S2[b * LT + tid], s2);
    }
}

// c[t] = (S2/S1) / ((sum_t S2/S1 + eps) * Z[t])
__global__ __launch_bounds__(64) void k3_coef(const float* Z, const float* S1,
                                              const float* S2, float* c) {
    int b = blockIdx.x, lane = threadIdx.x;
    float ts = S2[b * LT + lane] / S1[b * LT + lane];
    float tot = ts;
    #pragma unroll
    for (int o = 1; o < 64; o <<= 1) tot += __shfl_xor(tot, o, 64);
    c[b * LT + lane] = ts / ((tot + EPSV) * Z[b * LT + lane]);
}

// scores[row] = sum_t Sc[row][t]*c[t]; fused per-b min/max via uint atomics
// (scores > 0 strictly, so float order == uint order; min/max is order-safe).
__global__ __launch_bounds__(256) void k4_scores(const float* Sc, const float* c,
                                                 float* scores, uint32_t* mnmx) {
    __shared__ float bmn[4], bmx[4];
    int tid = threadIdx.x, wave = tid >> 6, lane = tid & 63;
    int rowbase = blockIdx.x * 32 + wave * 8;   // global row (b*LV+v); no b straddle
    int b = rowbase >> 14;
    float cr = c[b * LT + lane];
    float mn = 3.4e38f, mx = 0.f;
    #pragma unroll
    for (int g = 0; g < 8; ++g) {
        int row = rowbase + g;
        float x = Sc[(size_t)row * LT + lane] * cr;
        #pragma unroll
        for (int o = 1; o < 64; o <<= 1) x += __shfl_xor(x, o, 64);
        if (lane == 0) scores[row] = x;
        mn = fminf(mn, x); mx = fmaxf(mx, x);
    }
    if (lane == 0) { bmn[wave] = mn; bmx[wave] = mx; }
    __syncthreads();
    if (tid == 0) {
        float m0 = fminf(fminf(bmn[0], bmn[1]), fminf(bmn[2], bmn[3]));
        float m1 = fmaxf(fmaxf(bmx[0], bmx[1]), fmaxf(bmx[2], bmx[3]));
        atomicMin(&mnmx[b * 2], asu(m0));
        atomicMax(&mnmx[b * 2 + 1], asu(m1));
    }
}

// out = (scores - mn)/(mx - mn + eps); dtype per flag
__global__ __launch_bounds__(256) void k5_out(const float* scores, const uint32_t* mnmx,
                                              void* out, const int* flag) {
    int isf32 = flag[0];
    int i = blockIdx.x * 256 + threadIdx.x;
    if (i >= NB * LV) return;
    int b = i >> 14;
    float mn = asf(mnmx[b * 2]), mx = asf(mnmx[b * 2 + 1]);
    float val = (scores[i] - mn) / (mx - mn + EPSV);
    if (isf32) ((float*)out)[i] = val;
    else ((u16t*)out)[i] = f2bf(val);
}

extern "C" void kernel_launch(void* const* d_in, const int* in_sizes, int n_in,
                              void* d_out, int out_size, void* d_ws, size_t ws_size,
                              hipStream_t stream) {
    const void* t = d_in[0];   // [8,64,256]
    const void* v = d_in[1];   // [8,16384,256]
    char* w = (char*)d_ws;

    float*    Sc     = (float*)w;                       // 33,554,432 B
    u16t*     tnB    = (u16t*)(w + 33554432);           //    262,144 B
    float*    scores = (float*)(w + 33816576);          //    524,288 B
    float*    Z      = (float*)(w + 34340864);          // stats block
    float*    S1     = Z + 512;
    float*    S2     = Z + 1024;
    float*    c      = Z + 1536;
    uint32_t* mnmx   = (uint32_t*)(Z + 2048);           // 16 u32
    int*      flag   = (int*)(Z + 2064);

    k_init<<<1, 256, 0, stream>>>((const u16t*)v, Z, mnmx, flag);
    k1_tnorm<<<512, 256, 0, stream>>>(t, tnB, flag);
    k_gemm<<<dim3(128, NB), 256, 0, stream>>>(v, tnB, Sc, Z, S1, S2, flag);
    k3_coef<<<NB, 64, 0, stream>>>(Z, S1, S2, c);
    k4_scores<<<4096, 256, 0, stream>>>(Sc, c, scores, mnmx);
    k5_out<<<512, 256, 0, stream>>>(scores, mnmx, d_out, flag);
}